// Round 9
// baseline (178.607 us; speedup 1.0000x reference)
//
#include <hip/hip_runtime.h>
#include <hip/hip_bf16.h>

#define NN 512
#define DD 64
#define TOPK 20
#define BB 128

// =============== L1: fully parallel front-end ==================================
// blocks 0..511   : k2 GEMM (readlane version, byte-identical math to R7/R8)
// blocks 512..767 : kdot — cos numerators, 32x32 f64 dot tiles. Each dot computed
//                   sequentially by ONE thread, c ascending, x,y,z,w -> values
//                   bit-identical to R8's in-k1 dot loop.
// blocks 768..769 : norms (f64, same accumulation order as R8 kpre)
// blocks 770..771 : es_src/es_dst; block 768 also zeroes gstats.
__global__ __launch_bounds__(256) void L1_fused(const float* __restrict__ data,
                                                const float* __restrict__ emb,
                                                const float* __restrict__ fc_w,
                                                const float* __restrict__ fc_b,
                                                const float* __restrict__ attn_w,
                                                float* __restrict__ z,
                                                float* __restrict__ zsrc,
                                                float* __restrict__ zdst,
                                                double* __restrict__ cosM,
                                                double* __restrict__ nrm,
                                                float* __restrict__ es_src,
                                                float* __restrict__ es_dst,
                                                double* __restrict__ gstats) {
    __shared__ __align__(16) char smem[17408];
    const int bid = blockIdx.x, t = threadIdx.x;
    const int wid = t >> 6, lane = t & 63;

    if (bid < 512) {
        // ---------------- k2: GEMM, 4 waves x 32 rows/block --------------------
        float* WsT = (float*)smem;               // [64 f][65] : WsT[f][d]=fc_w[d][f]
        const float4* fcw4 = (const float4*)fc_w;
        for (int m = t; m < 1024; m += 256) {
            const int d = m >> 4, f4 = m & 15;
            float4 v = fcw4[d * 16 + f4];
            WsT[(f4 * 4 + 0) * 65 + d] = v.x;
            WsT[(f4 * 4 + 1) * 65 + d] = v.y;
            WsT[(f4 * 4 + 2) * 65 + d] = v.z;
            WsT[(f4 * 4 + 3) * 65 + d] = v.w;
        }
        __syncthreads();

        float Breg[64];
        #pragma unroll
        for (int f = 0; f < 64; ++f) Breg[f] = WsT[f * 65 + lane];

        const float bias = fc_b[lane];
        const float aw0  = attn_w[lane];
        const float aw2  = attn_w[128 + lane];
        const long rbase = ((long)bid * 4 + wid) * 32;

        #pragma unroll
        for (int g = 0; g < 4; ++g) {
            float a8[8];
            #pragma unroll
            for (int r = 0; r < 8; ++r)
                a8[r] = data[(rbase + g * 8 + r) * 64 + lane];
            #pragma unroll
            for (int r = 0; r < 8; ++r) {
                float acc = 0.f;
                #pragma unroll
                for (int f = 0; f < 64; ++f) {
                    const float af = __int_as_float(
                        __builtin_amdgcn_readlane(__float_as_int(a8[r]), f));
                    acc = fmaf(af, Breg[f], acc);
                }
                const float zb = acc + bias;
                const long row = rbase + g * 8 + r;
                z[row * 64 + lane] = zb;
                float p1 = zb * aw0, p2 = zb * aw2;
                #pragma unroll
                for (int off = 32; off > 0; off >>= 1) {
                    p1 += __shfl_xor(p1, off);
                    p2 += __shfl_xor(p2, off);
                }
                if (lane == 0) { zsrc[row] = p1; zdst[row] = p2; }
            }
        }
    } else if (bid < 768) {
        // ---------------- kdot: 32x32 f64 dot tile -----------------------------
        const int tile = bid - 512;               // 0..255 -> 16x16 tiles
        const int bi0 = (tile >> 4) * 32;
        const int bj0 = (tile & 15) * 32;
        float4* A4 = (float4*)smem;               // [32][17]
        float4* B4 = (float4*)(smem + 8704);      // [32][17]
        const float4* e4 = (const float4*)emb;

        for (int m = t; m < 512; m += 256) {
            const int r = m >> 4, c = m & 15;
            A4[r * 17 + c] = e4[(bi0 + r) * 16 + c];
            B4[r * 17 + c] = e4[(bj0 + r) * 16 + c];
        }
        __syncthreads();

        const int tr = t >> 4, tc = t & 15;
        #pragma unroll
        for (int rr = 0; rr < 2; ++rr) {
            #pragma unroll
            for (int cc = 0; cc < 2; ++cc) {
                const int r  = tr + rr * 16;
                const int cl = tc + cc * 16;
                double dot = 0.0;
                #pragma unroll
                for (int c = 0; c < 16; ++c) {
                    const float4 a = A4[r * 17 + c];   // query row i (broadcast)
                    const float4 b = B4[cl * 17 + c];  // candidate row j
                    dot += (double)a.x * (double)b.x;
                    dot += (double)a.y * (double)b.y;
                    dot += (double)a.z * (double)b.z;
                    dot += (double)a.w * (double)b.w;
                }
                cosM[(long)(bi0 + r) * NN + (bj0 + cl)] = dot;
            }
        }
    } else if (bid < 770) {
        // ---------------- norms (bit-identical order to R8) --------------------
        const int j = (bid - 768) * 256 + t;
        const float4* e4 = (const float4*)emb;
        double s = 0.0;
        #pragma unroll
        for (int c = 0; c < 16; ++c) {
            const float4 v = e4[j * 16 + c];
            const double vx = v.x, vy = v.y, vz = v.z, vw = v.w;
            s += vx * vx; s += vy * vy; s += vz * vz; s += vw * vw;
        }
        nrm[j] = sqrt(s);
        if (bid == 768 && t < 128) gstats[t] = 0.0;
    } else {
        // ---------------- es_src / es_dst --------------------------------------
        const int j = (bid - 770) * 256 + t;
        float s1 = 0.f, s2 = 0.f;
        #pragma unroll
        for (int c = 0; c < 64; ++c) {
            const float w = emb[j * 64 + c];
            s1 += w * attn_w[64 + c];
            s2 += w * attn_w[192 + c];
        }
        es_src[j] = s1;
        es_dst[j] = s2;
    }
}

// =============== KSEL: top-20 selection, one wave per node =====================
// v[slot] = cosM[i][slot*64+lane] / (nrm_i * nrm[slot*64+lane]) and the
// selection loop are expression-identical to R8 -> identical topk.
__global__ __launch_bounds__(256) void ksel(const double* __restrict__ cosM,
                                            const double* __restrict__ nrmArr,
                                            int* __restrict__ topk) {
    const int t = threadIdx.x;
    const int wid = t >> 6, lane = t & 63;
    const int i = blockIdx.x * 4 + wid;

    const double nrm_i = nrmArr[i];
    double v[8];
    #pragma unroll
    for (int s = 0; s < 8; ++s)
        v[s] = cosM[(long)i * NN + s * 64 + lane] / (nrm_i * nrmArr[s * 64 + lane]);

    for (int k = 0; k < TOPK; ++k) {
        double bv = v[0]; int bs = 0;
        #pragma unroll
        for (int s = 1; s < 8; ++s) if (v[s] > bv) { bv = v[s]; bs = s; }
        int bi = bs * 64 + lane;
        #pragma unroll
        for (int off = 32; off > 0; off >>= 1) {
            double ov = __shfl_xor(bv, off);
            int    oi = __shfl_xor(bi, off);
            if (ov > bv || (ov == bv && oi < bi)) { bv = ov; bi = oi; }
        }
        if (lane == 0) topk[i * TOPK + k] = bi;
        if ((bi & 63) == lane) v[bi >> 6] = -1e300;
    }
}

// =============== K3: LDS-staged gather + one-shot softmax + BN atomics =========
__global__ __launch_bounds__(256) void k3_attn(const float* __restrict__ z,
                                               const float* __restrict__ zsrc,
                                               const float* __restrict__ zdst,
                                               const float* __restrict__ es_src,
                                               const float* __restrict__ es_dst,
                                               const int* __restrict__ topk,
                                               const float* __restrict__ emb,
                                               const float* __restrict__ attn_b_p,
                                               float* __restrict__ rst,
                                               double* __restrict__ gstats) {
    __shared__ float  zs[512 * 16];          // 32 KB
    __shared__ double alf_pool[2560];        // 20 KB: alpha[256][20] / BN-reduce alias
    __shared__ unsigned short sIdx[256 * 20];// 10 KB
    float* alf = (float*)alf_pool;

    const int b    = blockIdx.x >> 2;
    const int dq   = blockIdx.x & 3;
    const int doff = dq * 16;
    const int t    = threadIdx.x;
    const float attn_b = *attn_b_p;
    const long b512 = (long)b * NN;

    float4* zs4 = (float4*)zs;
    for (int m = t; m < 2048; m += 256) {
        const int n = m >> 2, c4i = m & 3;
        zs4[m] = *(const float4*)(z + (b512 + n) * 64 + doff + c4i * 4);
    }
    __syncthreads();

    const int c4 = t & 3;
    const int rq = t >> 2;
    double s1[4] = {0,0,0,0}, s2[4] = {0,0,0,0};

    for (int chunk = 0; chunk < 2; ++chunk) {
        {
            const int n = chunk * 256 + t;
            const float sd = zdst[b512 + n] + es_dst[n] + attn_b;
            float ev[TOPK];
            float m0 = -1e30f;
            #pragma unroll
            for (int tt = 0; tt < TOPK; ++tt) {
                const int s = topk[n + tt * NN];   // scrambled flat edge list
                sIdx[t * TOPK + tt] = (unsigned short)s;
                float e = zsrc[b512 + s] + es_src[s] + sd;
                e = (e >= 0.f) ? e : 0.2f * e;
                ev[tt] = e;
                m0 = fmaxf(m0, e);
            }
            float dsum = 0.f;
            #pragma unroll
            for (int tt = 0; tt < TOPK; ++tt) { ev[tt] = __expf(ev[tt] - m0); dsum += ev[tt]; }
            const float inv = 1.0f / dsum;
            #pragma unroll
            for (int tt = 0; tt < TOPK; ++tt) alf[t * TOPK + tt] = ev[tt] * inv;
        }
        __syncthreads();

        #pragma unroll
        for (int it = 0; it < 4; ++it) {
            const int nl = it * 64 + rq;
            const int n  = chunk * 256 + nl;
            float4 acc = {0.f, 0.f, 0.f, 0.f};
            #pragma unroll
            for (int tt = 0; tt < TOPK; ++tt) {
                const float a = alf[nl * TOPK + tt];
                const float4 zv = zs4[(int)sIdx[nl * TOPK + tt] * 4 + c4];
                acc.x += a * zv.x; acc.y += a * zv.y; acc.z += a * zv.z; acc.w += a * zv.w;
            }
            const float4 ev = *(const float4*)&emb[n * 64 + doff + c4 * 4];
            float4 r;
            r.x = acc.x * ev.x; r.y = acc.y * ev.y; r.z = acc.z * ev.z; r.w = acc.w * ev.w;
            *(float4*)&rst[(b512 + n) * 64 + doff + c4 * 4] = r;
            s1[0] += (double)r.x; s2[0] += (double)r.x * (double)r.x;
            s1[1] += (double)r.y; s2[1] += (double)r.y * (double)r.y;
            s1[2] += (double)r.z; s2[2] += (double)r.z * (double)r.z;
            s1[3] += (double)r.w; s2[3] += (double)r.w * (double)r.w;
        }
        __syncthreads();
    }

    double* r1 = alf_pool;
    double* r2 = alf_pool + 1024;
    #pragma unroll
    for (int j = 0; j < 4; ++j) {
        r1[(c4 * 4 + j) * 64 + rq] = s1[j];
        r2[(c4 * 4 + j) * 64 + rq] = s2[j];
    }
    __syncthreads();
    if (t < 16) {
        double a = 0.0, bb = 0.0;
        for (int q = 0; q < 64; ++q) { a += r1[t * 64 + q]; bb += r2[t * 64 + q]; }
        atomicAdd(&gstats[doff + t], a);
        atomicAdd(&gstats[64 + doff + t], bb);
    }
}

// =============== K5: BN finalize (per-block) + apply + ReLU + out_w dot ========
__global__ __launch_bounds__(256) void k5_out(const float* __restrict__ rst,
                                              const double* __restrict__ gstats,
                                              const float* __restrict__ gamma,
                                              const float* __restrict__ beta,
                                              const float* __restrict__ out_w,
                                              const float* __restrict__ out_b_p,
                                              float* __restrict__ out) {
    __shared__ float scv[64], biv[64];
    const int t = threadIdx.x;
    if (t < 64) {
        const double M = (double)BB * (double)NN;
        const double s  = gstats[t];
        const double s2 = gstats[64 + t];
        const double mu  = s / M;
        const double var = s2 / M - mu * mu;
        const float scale = (float)((double)gamma[t] / sqrt(var + 1e-5));
        scv[t] = scale;
        biv[t] = beta[t] - (float)mu * scale;
    }
    __syncthreads();

    const int wid = t >> 6, lane = t & 63;
    const float sc = scv[lane], bi = biv[lane], ow = out_w[lane];
    const float ob = *out_b_p;
    const long rowbase = (long)blockIdx.x * 16 + wid * 4;
    float v[4];
    #pragma unroll
    for (int rr = 0; rr < 4; ++rr)
        v[rr] = fmaxf(rst[(rowbase + rr) * 64 + lane] * sc + bi, 0.f) * ow;
    #pragma unroll
    for (int off = 32; off > 0; off >>= 1)
        #pragma unroll
        for (int rr = 0; rr < 4; ++rr) v[rr] += __shfl_down(v[rr], off);
    if (lane == 0)
        #pragma unroll
        for (int rr = 0; rr < 4; ++rr) out[rowbase + rr] = v[rr] + ob;
}

extern "C" void kernel_launch(void* const* d_in, const int* in_sizes, int n_in,
                              void* d_out, int out_size, void* d_ws, size_t ws_size,
                              hipStream_t stream) {
    const float* data   = (const float*)d_in[0];
    const float* emb    = (const float*)d_in[1];
    const float* fc_w   = (const float*)d_in[2];
    const float* fc_b   = (const float*)d_in[3];
    const float* attn_w = (const float*)d_in[4];
    const float* attn_b = (const float*)d_in[5];
    const float* gamma  = (const float*)d_in[6];
    const float* beta   = (const float*)d_in[7];
    const float* out_w  = (const float*)d_in[8];
    const float* out_b  = (const float*)d_in[9];
    float* out = (float*)d_out;

    char* ws = (char*)d_ws;
    float*  z      = (float*) (ws + 0);            // 16 MB
    float*  rst    = (float*) (ws + 16777216);     // 16 MB
    float*  zsrc   = (float*) (ws + 33554432);     // 256 KB
    float*  zdst   = (float*) (ws + 33816576);     // 256 KB
    int*    topk   = (int*)   (ws + 34078720);     // 40 KB
    float*  es_src = (float*) (ws + 34119680);     // 2 KB
    float*  es_dst = (float*) (ws + 34121728);     // 2 KB
    double* gstats = (double*)(ws + 34123776);     // 1 KB
    double* nrm    = (double*)(ws + 34124800);     // 4 KB
    double* cosM   = (double*)(ws + 34131968);     // 2 MB

    L1_fused<<<772, 256, 0, stream>>>(data, emb, fc_w, fc_b, attn_w,
                                      z, zsrc, zdst, cosM, nrm,
                                      es_src, es_dst, gstats);
    ksel<<<128, 256, 0, stream>>>(cosM, nrm, topk);
    k3_attn<<<BB * 4, 256, 0, stream>>>(z, zsrc, zdst, es_src, es_dst, topk, emb,
                                        attn_b, rst, gstats);
    k5_out<<<4096, 256, 0, stream>>>(rst, gstats, gamma, beta, out_w, out_b, out);
}

// Round 10
// 151.816 us; speedup vs baseline: 1.1765x; 1.1765x over previous
//
#include <hip/hip_runtime.h>
#include <hip/hip_bf16.h>

#define NN 512
#define DD 64
#define TOPK 20
#define BB 128

// =============== L1: fully parallel front-end ==================================
// blocks 0..1023    : k2 GEMM — LDS-tile version (R2/R3-verified structure),
//                     float4 LDS reads, redA/redB aliased onto As after k-loop.
// blocks 1024..1279 : kdot — cos numerators, 32x32 f64 dot tiles (bit-identical
//                     values to R9).
// blocks 1280..1281 : norms (f64, bit-identical order); 1280 zeroes gstats.
// blocks 1282..1283 : es_src / es_dst.
__global__ __launch_bounds__(256) void L1_fused(const float* __restrict__ data,
                                                const float* __restrict__ emb,
                                                const float* __restrict__ fc_w,
                                                const float* __restrict__ fc_b,
                                                const float* __restrict__ attn_w,
                                                float* __restrict__ z,
                                                float* __restrict__ zsrc,
                                                float* __restrict__ zdst,
                                                double* __restrict__ cosM,
                                                double* __restrict__ nrm,
                                                float* __restrict__ es_src,
                                                float* __restrict__ es_dst,
                                                double* __restrict__ gstats) {
    __shared__ __align__(16) char smem[34816];
    const int bid = blockIdx.x, t = threadIdx.x;

    if (bid < 1024) {
        // ---------------- k2: GEMM 64x64 tile, float4 LDS ----------------------
        float (*As)[68]  = (float(*)[68])smem;             // 17408 B
        float (*WsT)[68] = (float(*)[68])(smem + 17408);   // 17408 B
        const long r0 = (long)bid * 64;
        const float4* data4 = (const float4*)data;
        const float4* fcw4  = (const float4*)fc_w;

        for (int m = t; m < 1024; m += 256) {
            const int r = m >> 4, c4 = m & 15;
            *(float4*)&As[r][c4 * 4] = data4[(r0 + r) * 16 + c4];
        }
        for (int m = t; m < 1024; m += 256) {
            const int d = m >> 4, f4 = m & 15;
            float4 v = fcw4[d * 16 + f4];
            WsT[f4 * 4 + 0][d] = v.x;
            WsT[f4 * 4 + 1][d] = v.y;
            WsT[f4 * 4 + 2][d] = v.z;
            WsT[f4 * 4 + 3][d] = v.w;
        }
        __syncthreads();

        const int tr = t >> 4, tc = t & 15;
        float acc[4][4] = {};
        for (int k0 = 0; k0 < 64; k0 += 4) {
            float4 a4[4], b4[4];
            #pragma unroll
            for (int i = 0; i < 4; ++i) a4[i] = *(float4*)&As[tr * 4 + i][k0];
            #pragma unroll
            for (int kk = 0; kk < 4; ++kk) b4[kk] = *(float4*)&WsT[k0 + kk][tc * 4];
            #pragma unroll
            for (int i = 0; i < 4; ++i) {
                acc[i][0] += a4[i].x * b4[0].x + a4[i].y * b4[1].x + a4[i].z * b4[2].x + a4[i].w * b4[3].x;
                acc[i][1] += a4[i].x * b4[0].y + a4[i].y * b4[1].y + a4[i].z * b4[2].y + a4[i].w * b4[3].y;
                acc[i][2] += a4[i].x * b4[0].z + a4[i].y * b4[1].z + a4[i].z * b4[2].z + a4[i].w * b4[3].z;
                acc[i][3] += a4[i].x * b4[0].w + a4[i].y * b4[1].w + a4[i].z * b4[2].w + a4[i].w * b4[3].w;
            }
        }
        float bias[4], aw0[4], aw2[4];
        #pragma unroll
        for (int j = 0; j < 4; ++j) {
            bias[j] = fc_b[tc * 4 + j];
            aw0[j]  = attn_w[tc * 4 + j];
            aw2[j]  = attn_w[128 + tc * 4 + j];
        }
        float zb[4][4];
        #pragma unroll
        for (int i = 0; i < 4; ++i) {
            #pragma unroll
            for (int j = 0; j < 4; ++j) zb[i][j] = acc[i][j] + bias[j];
            float4 vv; vv.x = zb[i][0]; vv.y = zb[i][1]; vv.z = zb[i][2]; vv.w = zb[i][3];
            *(float4*)&z[(r0 + tr * 4 + i) * 64 + tc * 4] = vv;
        }
        __syncthreads();   // all As/WsT reads done -> safe to alias

        float (*redA)[17] = (float(*)[17])smem;            // 4352 B (aliases As)
        float (*redB)[17] = (float(*)[17])(smem + 4352);   // 4352 B
        #pragma unroll
        for (int i = 0; i < 4; ++i) {
            redA[tr * 4 + i][tc] = zb[i][0] * aw0[0] + zb[i][1] * aw0[1] + zb[i][2] * aw0[2] + zb[i][3] * aw0[3];
            redB[tr * 4 + i][tc] = zb[i][0] * aw2[0] + zb[i][1] * aw2[1] + zb[i][2] * aw2[2] + zb[i][3] * aw2[3];
        }
        __syncthreads();
        if (t < 64) {
            float sA = 0.f, sB = 0.f;
            #pragma unroll
            for (int k = 0; k < 16; ++k) { sA += redA[t][k]; sB += redB[t][k]; }
            zsrc[r0 + t] = sA;
            zdst[r0 + t] = sB;
        }
    } else if (bid < 1280) {
        // ---------------- kdot: 32x32 f64 dot tile -----------------------------
        const int tile = bid - 1024;              // 0..255 -> 16x16 tiles
        const int bi0 = (tile >> 4) * 32;
        const int bj0 = (tile & 15) * 32;
        float4* A4 = (float4*)smem;               // [32][17]
        float4* B4 = (float4*)(smem + 8704);      // [32][17]
        const float4* e4 = (const float4*)emb;

        for (int m = t; m < 512; m += 256) {
            const int r = m >> 4, c = m & 15;
            A4[r * 17 + c] = e4[(bi0 + r) * 16 + c];
            B4[r * 17 + c] = e4[(bj0 + r) * 16 + c];
        }
        __syncthreads();

        const int tr = t >> 4, tc = t & 15;
        #pragma unroll
        for (int rr = 0; rr < 2; ++rr) {
            #pragma unroll
            for (int cc = 0; cc < 2; ++cc) {
                const int r  = tr + rr * 16;
                const int cl = tc + cc * 16;
                double dot = 0.0;
                #pragma unroll
                for (int c = 0; c < 16; ++c) {
                    const float4 a = A4[r * 17 + c];
                    const float4 b = B4[cl * 17 + c];
                    dot += (double)a.x * (double)b.x;
                    dot += (double)a.y * (double)b.y;
                    dot += (double)a.z * (double)b.z;
                    dot += (double)a.w * (double)b.w;
                }
                cosM[(long)(bi0 + r) * NN + (bj0 + cl)] = dot;
            }
        }
    } else if (bid < 1282) {
        // ---------------- norms (bit-identical order) --------------------------
        const int j = (bid - 1280) * 256 + t;
        const float4* e4 = (const float4*)emb;
        double s = 0.0;
        #pragma unroll
        for (int c = 0; c < 16; ++c) {
            const float4 v = e4[j * 16 + c];
            const double vx = v.x, vy = v.y, vz = v.z, vw = v.w;
            s += vx * vx; s += vy * vy; s += vz * vz; s += vw * vw;
        }
        nrm[j] = sqrt(s);
        if (bid == 1280 && t < 128) gstats[t] = 0.0;
    } else {
        // ---------------- es_src / es_dst --------------------------------------
        const int j = (bid - 1282) * 256 + t;
        float s1 = 0.f, s2 = 0.f;
        #pragma unroll
        for (int c = 0; c < 64; ++c) {
            const float w = emb[j * 64 + c];
            s1 += w * attn_w[64 + c];
            s2 += w * attn_w[192 + c];
        }
        es_src[j] = s1;
        es_dst[j] = s2;
    }
}

// =============== KSEL: top-20 selection, one wave per node =====================
__global__ __launch_bounds__(256) void ksel(const double* __restrict__ cosM,
                                            const double* __restrict__ nrmArr,
                                            int* __restrict__ topk) {
    const int t = threadIdx.x;
    const int wid = t >> 6, lane = t & 63;
    const int i = blockIdx.x * 4 + wid;

    const double nrm_i = nrmArr[i];
    double v[8];
    #pragma unroll
    for (int s = 0; s < 8; ++s)
        v[s] = cosM[(long)i * NN + s * 64 + lane] / (nrm_i * nrmArr[s * 64 + lane]);

    for (int k = 0; k < TOPK; ++k) {
        double bv = v[0]; int bs = 0;
        #pragma unroll
        for (int s = 1; s < 8; ++s) if (v[s] > bv) { bv = v[s]; bs = s; }
        int bi = bs * 64 + lane;
        #pragma unroll
        for (int off = 32; off > 0; off >>= 1) {
            double ov = __shfl_xor(bv, off);
            int    oi = __shfl_xor(bi, off);
            if (ov > bv || (ov == bv && oi < bi)) { bv = ov; bi = oi; }
        }
        if (lane == 0) topk[i * TOPK + k] = bi;
        if ((bi & 63) == lane) v[bi >> 6] = -1e300;
    }
}

// =============== K3: LDS-staged gather + one-shot softmax + BN atomics =========
__global__ __launch_bounds__(256) void k3_attn(const float* __restrict__ z,
                                               const float* __restrict__ zsrc,
                                               const float* __restrict__ zdst,
                                               const float* __restrict__ es_src,
                                               const float* __restrict__ es_dst,
                                               const int* __restrict__ topk,
                                               const float* __restrict__ emb,
                                               const float* __restrict__ attn_b_p,
                                               float* __restrict__ rst,
                                               double* __restrict__ gstats) {
    __shared__ float  zs[512 * 16];          // 32 KB
    __shared__ double alf_pool[2560];        // 20 KB: alpha[256][20] / BN-reduce alias
    __shared__ unsigned short sIdx[256 * 20];// 10 KB
    float* alf = (float*)alf_pool;

    const int b    = blockIdx.x >> 2;
    const int dq   = blockIdx.x & 3;
    const int doff = dq * 16;
    const int t    = threadIdx.x;
    const float attn_b = *attn_b_p;
    const long b512 = (long)b * NN;

    float4* zs4 = (float4*)zs;
    for (int m = t; m < 2048; m += 256) {
        const int n = m >> 2, c4i = m & 3;
        zs4[m] = *(const float4*)(z + (b512 + n) * 64 + doff + c4i * 4);
    }
    __syncthreads();

    const int c4 = t & 3;
    const int rq = t >> 2;
    double s1[4] = {0,0,0,0}, s2[4] = {0,0,0,0};

    for (int chunk = 0; chunk < 2; ++chunk) {
        {
            const int n = chunk * 256 + t;
            const float sd = zdst[b512 + n] + es_dst[n] + attn_b;
            float ev[TOPK];
            float m0 = -1e30f;
            #pragma unroll
            for (int tt = 0; tt < TOPK; ++tt) {
                const int s = topk[n + tt * NN];   // scrambled flat edge list
                sIdx[t * TOPK + tt] = (unsigned short)s;
                float e = zsrc[b512 + s] + es_src[s] + sd;
                e = (e >= 0.f) ? e : 0.2f * e;
                ev[tt] = e;
                m0 = fmaxf(m0, e);
            }
            float dsum = 0.f;
            #pragma unroll
            for (int tt = 0; tt < TOPK; ++tt) { ev[tt] = __expf(ev[tt] - m0); dsum += ev[tt]; }
            const float inv = 1.0f / dsum;
            #pragma unroll
            for (int tt = 0; tt < TOPK; ++tt) alf[t * TOPK + tt] = ev[tt] * inv;
        }
        __syncthreads();

        #pragma unroll
        for (int it = 0; it < 4; ++it) {
            const int nl = it * 64 + rq;
            const int n  = chunk * 256 + nl;
            float4 acc = {0.f, 0.f, 0.f, 0.f};
            #pragma unroll
            for (int tt = 0; tt < TOPK; ++tt) {
                const float a = alf[nl * TOPK + tt];
                const float4 zv = zs4[(int)sIdx[nl * TOPK + tt] * 4 + c4];
                acc.x += a * zv.x; acc.y += a * zv.y; acc.z += a * zv.z; acc.w += a * zv.w;
            }
            const float4 ev = *(const float4*)&emb[n * 64 + doff + c4 * 4];
            float4 r;
            r.x = acc.x * ev.x; r.y = acc.y * ev.y; r.z = acc.z * ev.z; r.w = acc.w * ev.w;
            *(float4*)&rst[(b512 + n) * 64 + doff + c4 * 4] = r;
            s1[0] += (double)r.x; s2[0] += (double)r.x * (double)r.x;
            s1[1] += (double)r.y; s2[1] += (double)r.y * (double)r.y;
            s1[2] += (double)r.z; s2[2] += (double)r.z * (double)r.z;
            s1[3] += (double)r.w; s2[3] += (double)r.w * (double)r.w;
        }
        __syncthreads();
    }

    double* r1 = alf_pool;
    double* r2 = alf_pool + 1024;
    #pragma unroll
    for (int j = 0; j < 4; ++j) {
        r1[(c4 * 4 + j) * 64 + rq] = s1[j];
        r2[(c4 * 4 + j) * 64 + rq] = s2[j];
    }
    __syncthreads();
    if (t < 16) {
        double a = 0.0, bb = 0.0;
        for (int q = 0; q < 64; ++q) { a += r1[t * 64 + q]; bb += r2[t * 64 + q]; }
        atomicAdd(&gstats[doff + t], a);
        atomicAdd(&gstats[64 + doff + t], bb);
    }
}

// =============== K5: BN finalize (per-block) + apply + ReLU + out_w dot ========
__global__ __launch_bounds__(256) void k5_out(const float* __restrict__ rst,
                                              const double* __restrict__ gstats,
                                              const float* __restrict__ gamma,
                                              const float* __restrict__ beta,
                                              const float* __restrict__ out_w,
                                              const float* __restrict__ out_b_p,
                                              float* __restrict__ out) {
    __shared__ float scv[64], biv[64];
    const int t = threadIdx.x;
    if (t < 64) {
        const double M = (double)BB * (double)NN;
        const double s  = gstats[t];
        const double s2 = gstats[64 + t];
        const double mu  = s / M;
        const double var = s2 / M - mu * mu;
        const float scale = (float)((double)gamma[t] / sqrt(var + 1e-5));
        scv[t] = scale;
        biv[t] = beta[t] - (float)mu * scale;
    }
    __syncthreads();

    const int wid = t >> 6, lane = t & 63;
    const float sc = scv[lane], bi = biv[lane], ow = out_w[lane];
    const float ob = *out_b_p;
    const long rowbase = (long)blockIdx.x * 16 + wid * 4;
    float v[4];
    #pragma unroll
    for (int rr = 0; rr < 4; ++rr)
        v[rr] = fmaxf(rst[(rowbase + rr) * 64 + lane] * sc + bi, 0.f) * ow;
    #pragma unroll
    for (int off = 32; off > 0; off >>= 1)
        #pragma unroll
        for (int rr = 0; rr < 4; ++rr) v[rr] += __shfl_down(v[rr], off);
    if (lane == 0)
        #pragma unroll
        for (int rr = 0; rr < 4; ++rr) out[rowbase + rr] = v[rr] + ob;
}

extern "C" void kernel_launch(void* const* d_in, const int* in_sizes, int n_in,
                              void* d_out, int out_size, void* d_ws, size_t ws_size,
                              hipStream_t stream) {
    const float* data   = (const float*)d_in[0];
    const float* emb    = (const float*)d_in[1];
    const float* fc_w   = (const float*)d_in[2];
    const float* fc_b   = (const float*)d_in[3];
    const float* attn_w = (const float*)d_in[4];
    const float* attn_b = (const float*)d_in[5];
    const float* gamma  = (const float*)d_in[6];
    const float* beta   = (const float*)d_in[7];
    const float* out_w  = (const float*)d_in[8];
    const float* out_b  = (const float*)d_in[9];
    float* out = (float*)d_out;

    char* ws = (char*)d_ws;
    float*  z      = (float*) (ws + 0);            // 16 MB
    float*  rst    = (float*) (ws + 16777216);     // 16 MB
    float*  zsrc   = (float*) (ws + 33554432);     // 256 KB
    float*  zdst   = (float*) (ws + 33816576);     // 256 KB
    int*    topk   = (int*)   (ws + 34078720);     // 40 KB
    float*  es_src = (float*) (ws + 34119680);     // 2 KB
    float*  es_dst = (float*) (ws + 34121728);     // 2 KB
    double* gstats = (double*)(ws + 34123776);     // 1 KB
    double* nrm    = (double*)(ws + 34124800);     // 4 KB
    double* cosM   = (double*)(ws + 34131968);     // 2 MB

    L1_fused<<<1284, 256, 0, stream>>>(data, emb, fc_w, fc_b, attn_w,
                                       z, zsrc, zdst, cosM, nrm,
                                       es_src, es_dst, gstats);
    ksel<<<128, 256, 0, stream>>>(cosM, nrm, topk);
    k3_attn<<<BB * 4, 256, 0, stream>>>(z, zsrc, zdst, es_src, es_dst, topk, emb,
                                        attn_b, rst, gstats);
    k5_out<<<4096, 256, 0, stream>>>(rst, gstats, gamma, beta, out_w, out_b, out);
}

// Round 11
// 142.981 us; speedup vs baseline: 1.2492x; 1.0618x over previous
//
#include <hip/hip_runtime.h>
#include <hip/hip_bf16.h>

#define NN 512
#define DD 64
#define TOPK 20
#define BB 128

// =============== KDOT_PRE: f64 heavy work, isolated register budget ============
// blocks 0..255 : cos numerators, 32x32 f64 dot tiles (bit-identical to R10)
// blocks 256..257: norms (f64, bit-identical order); 256 zeroes gstats
// blocks 258..259: es_src / es_dst
__global__ __launch_bounds__(256) void kdot_pre(const float* __restrict__ emb,
                                                const float* __restrict__ attn_w,
                                                double* __restrict__ cosM,
                                                double* __restrict__ nrm,
                                                float* __restrict__ es_src,
                                                float* __restrict__ es_dst,
                                                double* __restrict__ gstats) {
    __shared__ __align__(16) char smem[17408];
    const int bid = blockIdx.x, t = threadIdx.x;

    if (bid < 256) {
        const int bi0 = (bid >> 4) * 32;
        const int bj0 = (bid & 15) * 32;
        float4* A4 = (float4*)smem;               // [32][17]
        float4* B4 = (float4*)(smem + 8704);      // [32][17]
        const float4* e4 = (const float4*)emb;

        for (int m = t; m < 512; m += 256) {
            const int r = m >> 4, c = m & 15;
            A4[r * 17 + c] = e4[(bi0 + r) * 16 + c];
            B4[r * 17 + c] = e4[(bj0 + r) * 16 + c];
        }
        __syncthreads();

        const int tr = t >> 4, tc = t & 15;
        #pragma unroll
        for (int rr = 0; rr < 2; ++rr) {
            #pragma unroll
            for (int cc = 0; cc < 2; ++cc) {
                const int r  = tr + rr * 16;
                const int cl = tc + cc * 16;
                double dot = 0.0;
                #pragma unroll
                for (int c = 0; c < 16; ++c) {
                    const float4 a = A4[r * 17 + c];
                    const float4 b = B4[cl * 17 + c];
                    dot += (double)a.x * (double)b.x;
                    dot += (double)a.y * (double)b.y;
                    dot += (double)a.z * (double)b.z;
                    dot += (double)a.w * (double)b.w;
                }
                cosM[(long)(bi0 + r) * NN + (bj0 + cl)] = dot;
            }
        }
    } else if (bid < 258) {
        const int j = (bid - 256) * 256 + t;
        const float4* e4 = (const float4*)emb;
        double s = 0.0;
        #pragma unroll
        for (int c = 0; c < 16; ++c) {
            const float4 v = e4[j * 16 + c];
            const double vx = v.x, vy = v.y, vz = v.z, vw = v.w;
            s += vx * vx; s += vy * vy; s += vz * vz; s += vw * vw;
        }
        nrm[j] = sqrt(s);
        if (bid == 256 && t < 128) gstats[t] = 0.0;
    } else {
        const int j = (bid - 258) * 256 + t;
        float s1 = 0.f, s2 = 0.f;
        #pragma unroll
        for (int c = 0; c < 64; ++c) {
            const float w = emb[j * 64 + c];
            s1 += w * attn_w[64 + c];
            s2 += w * attn_w[192 + c];
        }
        es_src[j] = s1;
        es_dst[j] = s2;
    }
}

// =============== KGEMM_SEL: lean f32 GEMM + topk selection =====================
// blocks 0..1023   : k2 GEMM 64x64 tile (expressions identical to R10 -> same z)
// blocks 1024..1151: ksel — reads cosM/nrm written by kdot_pre (prior launch).
__global__ __launch_bounds__(256) void kgemm_sel(const float* __restrict__ data,
                                                 const float* __restrict__ fc_w,
                                                 const float* __restrict__ fc_b,
                                                 const float* __restrict__ attn_w,
                                                 const double* __restrict__ cosM,
                                                 const double* __restrict__ nrmArr,
                                                 float* __restrict__ z,
                                                 float* __restrict__ zsrc,
                                                 float* __restrict__ zdst,
                                                 int* __restrict__ topk) {
    __shared__ __align__(16) char smem[34816];
    const int bid = blockIdx.x, t = threadIdx.x;

    if (bid < 1024) {
        // ---------------- GEMM 64x64 tile, float4 LDS --------------------------
        float (*As)[68]  = (float(*)[68])smem;             // 17408 B
        float (*WsT)[68] = (float(*)[68])(smem + 17408);   // 17408 B
        const long r0 = (long)bid * 64;
        const float4* data4 = (const float4*)data;
        const float4* fcw4  = (const float4*)fc_w;

        for (int m = t; m < 1024; m += 256) {
            const int r = m >> 4, c4 = m & 15;
            *(float4*)&As[r][c4 * 4] = data4[(r0 + r) * 16 + c4];
        }
        for (int m = t; m < 1024; m += 256) {
            const int d = m >> 4, f4 = m & 15;
            float4 v = fcw4[d * 16 + f4];
            WsT[f4 * 4 + 0][d] = v.x;
            WsT[f4 * 4 + 1][d] = v.y;
            WsT[f4 * 4 + 2][d] = v.z;
            WsT[f4 * 4 + 3][d] = v.w;
        }
        __syncthreads();

        const int tr = t >> 4, tc = t & 15;
        float acc[4][4] = {};
        for (int k0 = 0; k0 < 64; k0 += 4) {
            float4 a4[4], b4[4];
            #pragma unroll
            for (int i = 0; i < 4; ++i) a4[i] = *(float4*)&As[tr * 4 + i][k0];
            #pragma unroll
            for (int kk = 0; kk < 4; ++kk) b4[kk] = *(float4*)&WsT[k0 + kk][tc * 4];
            #pragma unroll
            for (int i = 0; i < 4; ++i) {
                acc[i][0] += a4[i].x * b4[0].x + a4[i].y * b4[1].x + a4[i].z * b4[2].x + a4[i].w * b4[3].x;
                acc[i][1] += a4[i].x * b4[0].y + a4[i].y * b4[1].y + a4[i].z * b4[2].y + a4[i].w * b4[3].y;
                acc[i][2] += a4[i].x * b4[0].z + a4[i].y * b4[1].z + a4[i].z * b4[2].z + a4[i].w * b4[3].z;
                acc[i][3] += a4[i].x * b4[0].w + a4[i].y * b4[1].w + a4[i].z * b4[2].w + a4[i].w * b4[3].w;
            }
        }
        float bias[4], aw0[4], aw2[4];
        #pragma unroll
        for (int j = 0; j < 4; ++j) {
            bias[j] = fc_b[tc * 4 + j];
            aw0[j]  = attn_w[tc * 4 + j];
            aw2[j]  = attn_w[128 + tc * 4 + j];
        }
        float zb[4][4];
        #pragma unroll
        for (int i = 0; i < 4; ++i) {
            #pragma unroll
            for (int j = 0; j < 4; ++j) zb[i][j] = acc[i][j] + bias[j];
            float4 vv; vv.x = zb[i][0]; vv.y = zb[i][1]; vv.z = zb[i][2]; vv.w = zb[i][3];
            *(float4*)&z[(r0 + tr * 4 + i) * 64 + tc * 4] = vv;
        }
        __syncthreads();   // all As/WsT reads done -> safe to alias

        float (*redA)[17] = (float(*)[17])smem;            // aliases As
        float (*redB)[17] = (float(*)[17])(smem + 4352);
        #pragma unroll
        for (int i = 0; i < 4; ++i) {
            redA[tr * 4 + i][tc] = zb[i][0] * aw0[0] + zb[i][1] * aw0[1] + zb[i][2] * aw0[2] + zb[i][3] * aw0[3];
            redB[tr * 4 + i][tc] = zb[i][0] * aw2[0] + zb[i][1] * aw2[1] + zb[i][2] * aw2[2] + zb[i][3] * aw2[3];
        }
        __syncthreads();
        if (t < 64) {
            float sA = 0.f, sB = 0.f;
            #pragma unroll
            for (int k = 0; k < 16; ++k) { sA += redA[t][k]; sB += redB[t][k]; }
            zsrc[r0 + t] = sA;
            zdst[r0 + t] = sB;
        }
    } else {
        // ---------------- ksel: top-20, one wave per node ----------------------
        const int wid = t >> 6, lane = t & 63;
        const int i = (bid - 1024) * 4 + wid;

        const double nrm_i = nrmArr[i];
        double v[8];
        #pragma unroll
        for (int s = 0; s < 8; ++s)
            v[s] = cosM[(long)i * NN + s * 64 + lane] / (nrm_i * nrmArr[s * 64 + lane]);

        for (int k = 0; k < TOPK; ++k) {
            double bv = v[0]; int bs = 0;
            #pragma unroll
            for (int s = 1; s < 8; ++s) if (v[s] > bv) { bv = v[s]; bs = s; }
            int bi = bs * 64 + lane;
            #pragma unroll
            for (int off = 32; off > 0; off >>= 1) {
                double ov = __shfl_xor(bv, off);
                int    oi = __shfl_xor(bi, off);
                if (ov > bv || (ov == bv && oi < bi)) { bv = ov; bi = oi; }
            }
            if (lane == 0) topk[i * TOPK + k] = bi;
            if ((bi & 63) == lane) v[bi >> 6] = -1e300;
        }
    }
}

// =============== K3: LDS-staged gather + one-shot softmax + BN atomics =========
__global__ __launch_bounds__(256) void k3_attn(const float* __restrict__ z,
                                               const float* __restrict__ zsrc,
                                               const float* __restrict__ zdst,
                                               const float* __restrict__ es_src,
                                               const float* __restrict__ es_dst,
                                               const int* __restrict__ topk,
                                               const float* __restrict__ emb,
                                               const float* __restrict__ attn_b_p,
                                               float* __restrict__ rst,
                                               double* __restrict__ gstats) {
    __shared__ float  zs[512 * 16];          // 32 KB
    __shared__ double alf_pool[2560];        // 20 KB: alpha[256][20] / BN-reduce alias
    __shared__ unsigned short sIdx[256 * 20];// 10 KB
    float* alf = (float*)alf_pool;

    const int b    = blockIdx.x >> 2;
    const int dq   = blockIdx.x & 3;
    const int doff = dq * 16;
    const int t    = threadIdx.x;
    const float attn_b = *attn_b_p;
    const long b512 = (long)b * NN;

    float4* zs4 = (float4*)zs;
    for (int m = t; m < 2048; m += 256) {
        const int n = m >> 2, c4i = m & 3;
        zs4[m] = *(const float4*)(z + (b512 + n) * 64 + doff + c4i * 4);
    }
    __syncthreads();

    const int c4 = t & 3;
    const int rq = t >> 2;
    double s1[4] = {0,0,0,0}, s2[4] = {0,0,0,0};

    for (int chunk = 0; chunk < 2; ++chunk) {
        {
            const int n = chunk * 256 + t;
            const float sd = zdst[b512 + n] + es_dst[n] + attn_b;
            float ev[TOPK];
            float m0 = -1e30f;
            #pragma unroll
            for (int tt = 0; tt < TOPK; ++tt) {
                const int s = topk[n + tt * NN];   // scrambled flat edge list
                sIdx[t * TOPK + tt] = (unsigned short)s;
                float e = zsrc[b512 + s] + es_src[s] + sd;
                e = (e >= 0.f) ? e : 0.2f * e;
                ev[tt] = e;
                m0 = fmaxf(m0, e);
            }
            float dsum = 0.f;
            #pragma unroll
            for (int tt = 0; tt < TOPK; ++tt) { ev[tt] = __expf(ev[tt] - m0); dsum += ev[tt]; }
            const float inv = 1.0f / dsum;
            #pragma unroll
            for (int tt = 0; tt < TOPK; ++tt) alf[t * TOPK + tt] = ev[tt] * inv;
        }
        __syncthreads();

        #pragma unroll
        for (int it = 0; it < 4; ++it) {
            const int nl = it * 64 + rq;
            const int n  = chunk * 256 + nl;
            float4 acc = {0.f, 0.f, 0.f, 0.f};
            #pragma unroll
            for (int tt = 0; tt < TOPK; ++tt) {
                const float a = alf[nl * TOPK + tt];
                const float4 zv = zs4[(int)sIdx[nl * TOPK + tt] * 4 + c4];
                acc.x += a * zv.x; acc.y += a * zv.y; acc.z += a * zv.z; acc.w += a * zv.w;
            }
            const float4 ev = *(const float4*)&emb[n * 64 + doff + c4 * 4];
            float4 r;
            r.x = acc.x * ev.x; r.y = acc.y * ev.y; r.z = acc.z * ev.z; r.w = acc.w * ev.w;
            *(float4*)&rst[(b512 + n) * 64 + doff + c4 * 4] = r;
            s1[0] += (double)r.x; s2[0] += (double)r.x * (double)r.x;
            s1[1] += (double)r.y; s2[1] += (double)r.y * (double)r.y;
            s1[2] += (double)r.z; s2[2] += (double)r.z * (double)r.z;
            s1[3] += (double)r.w; s2[3] += (double)r.w * (double)r.w;
        }
        __syncthreads();
    }

    double* r1 = alf_pool;
    double* r2 = alf_pool + 1024;
    #pragma unroll
    for (int j = 0; j < 4; ++j) {
        r1[(c4 * 4 + j) * 64 + rq] = s1[j];
        r2[(c4 * 4 + j) * 64 + rq] = s2[j];
    }
    __syncthreads();
    if (t < 16) {
        double a = 0.0, bb = 0.0;
        for (int q = 0; q < 64; ++q) { a += r1[t * 64 + q]; bb += r2[t * 64 + q]; }
        atomicAdd(&gstats[doff + t], a);
        atomicAdd(&gstats[64 + doff + t], bb);
    }
}

// =============== K5: BN finalize (per-block) + apply + ReLU + out_w dot ========
__global__ __launch_bounds__(256) void k5_out(const float* __restrict__ rst,
                                              const double* __restrict__ gstats,
                                              const float* __restrict__ gamma,
                                              const float* __restrict__ beta,
                                              const float* __restrict__ out_w,
                                              const float* __restrict__ out_b_p,
                                              float* __restrict__ out) {
    __shared__ float scv[64], biv[64];
    const int t = threadIdx.x;
    if (t < 64) {
        const double M = (double)BB * (double)NN;
        const double s  = gstats[t];
        const double s2 = gstats[64 + t];
        const double mu  = s / M;
        const double var = s2 / M - mu * mu;
        const float scale = (float)((double)gamma[t] / sqrt(var + 1e-5));
        scv[t] = scale;
        biv[t] = beta[t] - (float)mu * scale;
    }
    __syncthreads();

    const int wid = t >> 6, lane = t & 63;
    const float sc = scv[lane], bi = biv[lane], ow = out_w[lane];
    const float ob = *out_b_p;
    const long rowbase = (long)blockIdx.x * 16 + wid * 4;
    float v[4];
    #pragma unroll
    for (int rr = 0; rr < 4; ++rr)
        v[rr] = fmaxf(rst[(rowbase + rr) * 64 + lane] * sc + bi, 0.f) * ow;
    #pragma unroll
    for (int off = 32; off > 0; off >>= 1)
        #pragma unroll
        for (int rr = 0; rr < 4; ++rr) v[rr] += __shfl_down(v[rr], off);
    if (lane == 0)
        #pragma unroll
        for (int rr = 0; rr < 4; ++rr) out[rowbase + rr] = v[rr] + ob;
}

extern "C" void kernel_launch(void* const* d_in, const int* in_sizes, int n_in,
                              void* d_out, int out_size, void* d_ws, size_t ws_size,
                              hipStream_t stream) {
    const float* data   = (const float*)d_in[0];
    const float* emb    = (const float*)d_in[1];
    const float* fc_w   = (const float*)d_in[2];
    const float* fc_b   = (const float*)d_in[3];
    const float* attn_w = (const float*)d_in[4];
    const float* attn_b = (const float*)d_in[5];
    const float* gamma  = (const float*)d_in[6];
    const float* beta   = (const float*)d_in[7];
    const float* out_w  = (const float*)d_in[8];
    const float* out_b  = (const float*)d_in[9];
    float* out = (float*)d_out;

    char* ws = (char*)d_ws;
    float*  z      = (float*) (ws + 0);            // 16 MB
    float*  rst    = (float*) (ws + 16777216);     // 16 MB
    float*  zsrc   = (float*) (ws + 33554432);     // 256 KB
    float*  zdst   = (float*) (ws + 33816576);     // 256 KB
    int*    topk   = (int*)   (ws + 34078720);     // 40 KB
    float*  es_src = (float*) (ws + 34119680);     // 2 KB
    float*  es_dst = (float*) (ws + 34121728);     // 2 KB
    double* gstats = (double*)(ws + 34123776);     // 1 KB
    double* nrm    = (double*)(ws + 34124800);     // 4 KB
    double* cosM   = (double*)(ws + 34131968);     // 2 MB

    kdot_pre<<<260, 256, 0, stream>>>(emb, attn_w, cosM, nrm, es_src, es_dst, gstats);
    kgemm_sel<<<1152, 256, 0, stream>>>(data, fc_w, fc_b, attn_w, cosM, nrm,
                                        z, zsrc, zdst, topk);
    k3_attn<<<BB * 4, 256, 0, stream>>>(z, zsrc, zdst, es_src, es_dst, topk, emb,
                                        attn_b, rst, gstats);
    k5_out<<<4096, 256, 0, stream>>>(rst, gstats, gamma, beta, out_w, out_b, out);
}